// Round 10
// baseline (6718.212 us; speedup 1.0000x reference)
//
#include <hip/hip_runtime.h>
#include <hip/hip_bf16.h>
#include <hip/hip_fp16.h>
#include <cstdint>

#define DDAYS 5
#define TT 8192
#define FF 768
#define HH 64
#define GG 256  // 4*H

__device__ __forceinline__ float fast_tanh(float x) {
    return 1.f - 2.f / (__expf(2.f * x) + 1.f);
}
__device__ __forceinline__ float fast_sig(float x) {
    return 1.f / (1.f + __expf(-x));
}

// ---------------------------------------------------------------------------
// Kernel 1: ux[m][g] = sum_f A[m][f] * B[g][f]   (bias added later in scan)
// ---------------------------------------------------------------------------
__global__ __launch_bounds__(256, 2) void gemm_ux(
    const float* __restrict__ A, const float* __restrict__ B,
    float* __restrict__ C)
{
    __shared__ __align__(16) float As[16][132];
    __shared__ __align__(16) float Bs[16][132];
    const int tid = threadIdx.x;
    const int m0 = blockIdx.x * 128;
    const int n0 = blockIdx.y * 128;
    const int tx = tid & 15, ty = tid >> 4;
    const int i0 = tx * 8, j0 = ty * 8;
    const int lrow = tid >> 2, lc4 = tid & 3;

    const float* Ap = A + (size_t)(m0 + lrow) * FF + lc4 * 4;
    const float* Bp = B + (size_t)(n0 + lrow) * FF + lc4 * 4;

    float4 pa0 = *(const float4*)(Ap);
    float4 pa1 = *(const float4*)(Ap + 64 * FF);
    float4 pb0 = *(const float4*)(Bp);
    float4 pb1 = *(const float4*)(Bp + 64 * FF);

    float acc[8][8] = {};

    for (int kt = 0; kt < FF / 16; ++kt) {
        __syncthreads();
        {
            const int kk = lc4 * 4;
            As[kk + 0][lrow] = pa0.x; As[kk + 1][lrow] = pa0.y;
            As[kk + 2][lrow] = pa0.z; As[kk + 3][lrow] = pa0.w;
            As[kk + 0][lrow + 64] = pa1.x; As[kk + 1][lrow + 64] = pa1.y;
            As[kk + 2][lrow + 64] = pa1.z; As[kk + 3][lrow + 64] = pa1.w;
            Bs[kk + 0][lrow] = pb0.x; Bs[kk + 1][lrow] = pb0.y;
            Bs[kk + 2][lrow] = pb0.z; Bs[kk + 3][lrow] = pb0.w;
            Bs[kk + 0][lrow + 64] = pb1.x; Bs[kk + 1][lrow + 64] = pb1.y;
            Bs[kk + 2][lrow + 64] = pb1.z; Bs[kk + 3][lrow + 64] = pb1.w;
        }
        __syncthreads();
        if (kt + 1 < FF / 16) {
            const int k0 = (kt + 1) * 16;
            pa0 = *(const float4*)(Ap + k0);
            pa1 = *(const float4*)(Ap + 64 * FF + k0);
            pb0 = *(const float4*)(Bp + k0);
            pb1 = *(const float4*)(Bp + 64 * FF + k0);
        }
#pragma unroll
        for (int k = 0; k < 16; ++k) {
            float a[8], b[8];
            *(float4*)&a[0] = *(const float4*)&As[k][i0];
            *(float4*)&a[4] = *(const float4*)&As[k][i0 + 4];
            *(float4*)&b[0] = *(const float4*)&Bs[k][j0];
            *(float4*)&b[4] = *(const float4*)&Bs[k][j0 + 4];
#pragma unroll
            for (int r = 0; r < 8; ++r)
#pragma unroll
                for (int c = 0; c < 8; ++c)
                    acc[r][c] = fmaf(a[r], b[c], acc[r][c]);
        }
    }
#pragma unroll
    for (int r = 0; r < 8; ++r) {
        float4 s0 = make_float4(acc[r][0], acc[r][1], acc[r][2], acc[r][3]);
        float4 s1 = make_float4(acc[r][4], acc[r][5], acc[r][6], acc[r][7]);
        float* Cp = C + (size_t)(m0 + i0 + r) * GG + n0 + j0;
        *(float4*)Cp = s0;
        *(float4*)(Cp + 4) = s1;
    }
}

// ---------------------------------------------------------------------------
// Kernel 2: TimeLSTM scan. ONE 64-lane wave per day; lane jj owns column jj
// and ALL FOUR gate rows (f,i,o,g) plus the W_d row. No barrier, no shuffles,
// NO inline asm in the loop.
// R10: dots via __hfma2 (v_pk_fma_f16, 2 f16 MACs/instr) with pure-C body --
// R8/R9's inline-asm dot2 made the allocator spill the 160-VGPR weight set
// (VGPR=132) and rematerialize UNCOALESCED weight loads from L2 every step
// (~1300 cyc stall). Pure-C bodies kept weights resident in R5 (VGPR=104)
// and R7 (VGPR=216). amdgpu_waves_per_eu(1,1) tells the allocator occupancy
// is 1 wave/EU regardless of VGPR count -> no reason to economize registers.
// Accuracy: two 16-deep f16 accumulator chains per row (~5e-4 on pre-acts;
// h/c already f16-quantized and absmax has been 0.0).
// ---------------------------------------------------------------------------
__attribute__((amdgpu_waves_per_eu(1, 1)))
__global__ __launch_bounds__(64) void scan_kernel(
    const float* __restrict__ ux, const float* __restrict__ ts,
    const float* __restrict__ Ww, const float* __restrict__ Wb,
    const float* __restrict__ Ub,
    const float* __restrict__ Dw, const float* __restrict__ Db,
    float* __restrict__ y, float* __restrict__ hfin)
{
    const int d = blockIdx.x;
    const int jj = threadIdx.x;  // column 0..63

    // weights: 4 gate rows (f,i,o,g) + W_d row, packed __half2 in registers
    __half2 wg[4][32];
    __half2 wd[32];
    float bias[4];
#pragma unroll
    for (int g = 0; g < 4; ++g) {
        const float2* p = (const float2*)(Ww + (size_t)(g * 64 + jj) * 64);
#pragma unroll
        for (int k = 0; k < 32; ++k) {
            float2 v = p[k];
            wg[g][k] = __floats2half2_rn(v.x, v.y);
        }
        bias[g] = Wb[g * 64 + jj] + Ub[g * 64 + jj];
    }
    {
        const float2* p = (const float2*)(Dw + (size_t)jj * 64);
#pragma unroll
        for (int k = 0; k < 32; ++k) {
            float2 v = p[k];
            wd[k] = __floats2half2_rn(v.x, v.y);
        }
    }
    const float wdb = Db[jj];

    __shared__ __align__(16) __half h_lds[64];
    __shared__ __align__(16) __half c_lds[64];
    h_lds[jj] = __float2half(0.f);
    c_lds[jj] = __float2half(0.f);
    __builtin_amdgcn_s_barrier();  // one-time init visibility (1 wave: cheap)

    const float* uxd = ux + (size_t)d * TT * GG + jj;  // +0/64/128/192 per gate
    const float* tsd = ts + (size_t)d * TT;
    float* yd = y + (size_t)d * TT * HH;

    // 4-step rolling prefetch of u (4 gates) and t
    float uf[4][4], tp[4];
#pragma unroll
    for (int i = 0; i < 4; ++i) {
        const float* up = uxd + (size_t)i * GG;
        uf[i][0] = up[0];
        uf[i][1] = up[64];
        uf[i][2] = up[128];
        uf[i][3] = up[192];
        tp[i] = tsd[i];
    }

    float c_old = 0.f;
    float hn = 0.f;

    for (int t = 0; t < TT; t += 4) {
#pragma unroll
        for (int i = 0; i < 4; ++i) {
            const int tc = t + i;
            const float uF = uf[i][0], uI = uf[i][1];
            const float uO = uf[i][2], uG = uf[i][3];
            const float tcur = tp[i];
            {   // prefetch step tc+4
                int tn = tc + 4; if (tn > TT - 1) tn = TT - 1;
                const float* up = uxd + (size_t)tn * GG;
                uf[i][0] = up[0];
                uf[i][1] = up[64];
                uf[i][2] = up[128];
                uf[i][3] = up[192];
                tp[i] = tsd[tn];
            }

            // broadcast h (8x b128) and c (8x b128) from LDS
            __half2 hp[32], cp[32];
            {
                const uint4* hb = (const uint4*)&h_lds[0];
                const uint4* cb = (const uint4*)&c_lds[0];
#pragma unroll
                for (int k = 0; k < 8; ++k) {
                    uint4 v = hb[k];
                    hp[4 * k + 0] = __builtin_bit_cast(__half2, v.x);
                    hp[4 * k + 1] = __builtin_bit_cast(__half2, v.y);
                    hp[4 * k + 2] = __builtin_bit_cast(__half2, v.z);
                    hp[4 * k + 3] = __builtin_bit_cast(__half2, v.w);
                    uint4 w = cb[k];
                    cp[4 * k + 0] = __builtin_bit_cast(__half2, w.x);
                    cp[4 * k + 1] = __builtin_bit_cast(__half2, w.y);
                    cp[4 * k + 2] = __builtin_bit_cast(__half2, w.z);
                    cp[4 * k + 3] = __builtin_bit_cast(__half2, w.w);
                }
            }

            // five 64-dots via v_pk_fma_f16: 2 f16x2 accumulator chains each
            const __half2 z2 = __float2half2_rn(0.f);
            __half2 aF0 = z2, aF1 = z2, aI0 = z2, aI1 = z2;
            __half2 aO0 = z2, aO1 = z2, aG0 = z2, aG1 = z2;
            __half2 aD0 = z2, aD1 = z2;
#pragma unroll
            for (int k = 0; k < 32; k += 2) {
                aF0 = __hfma2(wg[0][k],     hp[k],     aF0);
                aF1 = __hfma2(wg[0][k + 1], hp[k + 1], aF1);
                aI0 = __hfma2(wg[1][k],     hp[k],     aI0);
                aI1 = __hfma2(wg[1][k + 1], hp[k + 1], aI1);
                aO0 = __hfma2(wg[2][k],     hp[k],     aO0);
                aO1 = __hfma2(wg[2][k + 1], hp[k + 1], aO1);
                aG0 = __hfma2(wg[3][k],     hp[k],     aG0);
                aG1 = __hfma2(wg[3][k + 1], hp[k + 1], aG1);
                aD0 = __hfma2(wd[k],        cp[k],     aD0);
                aD1 = __hfma2(wd[k + 1],    cp[k + 1], aD1);
            }
            const float dF = (__low2float(aF0) + __low2float(aF1)) +
                             (__high2float(aF0) + __high2float(aF1));
            const float dI = (__low2float(aI0) + __low2float(aI1)) +
                             (__high2float(aI0) + __high2float(aI1));
            const float dO = (__low2float(aO0) + __low2float(aO1)) +
                             (__high2float(aO0) + __high2float(aO1));
            const float dG = (__low2float(aG0) + __low2float(aG1)) +
                             (__high2float(aG0) + __high2float(aG1));
            const float dD = (__low2float(aD0) + __low2float(aD1)) +
                             (__high2float(aD0) + __high2float(aD1));

            const float cs1 = fast_tanh(dD + wdb);
            const float f  = fast_sig(dF + bias[0] + uF);
            const float ii = fast_sig(dI + bias[1] + uI);
            const float oo = fast_sig(dO + bias[2] + uO);
            const float gg = fast_tanh(dG + bias[3] + uG);

            const float cadj = fmaf(cs1, tcur - 1.f, c_old);
            const float cn = fmaf(f, cadj, ii * gg);
            hn = oo * fast_tanh(cn);
            c_old = cn;

            // publish state (single-wave DS is in-order: next step's reads
            // see these writes; compiler inserts counted lgkm waits)
            h_lds[jj] = __float2half(hn);
            c_lds[jj] = __float2half(cn);

            yd[(size_t)tc * HH + jj] = fast_tanh(oo);
        }
    }
    hfin[d * 64 + jj] = hn;  // exact f32 final state
}

// ---------------------------------------------------------------------------
// Kernel 3: score[d][t] = V . tanh(q_d + W2 y_dt + b2) + Vb
// ---------------------------------------------------------------------------
#define TW 32
__global__ __launch_bounds__(256) void score_kernel(
    const float* __restrict__ y, const float* __restrict__ hfin,
    const float* __restrict__ W1, const float* __restrict__ b1,
    const float* __restrict__ W2, const float* __restrict__ b2,
    const float* __restrict__ Vw, const float* __restrict__ Vb,
    float* __restrict__ score)
{
    const int d = blockIdx.y;
    const int tid = threadIdx.x;
    const int lane = tid & 63, wv = tid >> 6;
    __shared__ __align__(16) float hf[64];
    __shared__ float qs[64];
    if (tid < 64) hf[tid] = hfin[d * 64 + tid];
    __syncthreads();
    if (tid < 64) {
        float acc = b1[tid];
#pragma unroll
        for (int k = 0; k < 16; k++) {
            float4 w = *(const float4*)&W1[tid * 64 + 4 * k];
            float4 h4 = *(const float4*)&hf[4 * k];
            acc += w.x * h4.x + w.y * h4.y + w.z * h4.z + w.w * h4.w;
        }
        qs[tid] = acc;
    }
    __syncthreads();

    float w2[64];
#pragma unroll
    for (int k = 0; k < 16; k++) {
        float4 v = *(const float4*)&W2[lane * 64 + 4 * k];
        w2[4 * k] = v.x; w2[4 * k + 1] = v.y;
        w2[4 * k + 2] = v.z; w2[4 * k + 3] = v.w;
    }
    const float qb = qs[lane] + b2[lane];
    const float vr = Vw[lane];
    const float vb = Vb[0];
    const int tbase = blockIdx.x * (4 * TW) + wv * TW;
    const float* yd = y + (size_t)d * TT * HH;

    for (int i = 0; i < TW; i++) {
        const int t = tbase + i;
        const float* yrow = yd + (size_t)t * HH;
        float a0 = 0.f, a1 = 0.f, a2 = 0.f, a3 = 0.f;
#pragma unroll
        for (int k = 0; k < 64; k += 4) {
            float4 yv = *(const float4*)&yrow[k];
            a0 = fmaf(yv.x, w2[k], a0);
            a1 = fmaf(yv.y, w2[k + 1], a1);
            a2 = fmaf(yv.z, w2[k + 2], a2);
            a3 = fmaf(yv.w, w2[k + 3], a3);
        }
        float v = fast_tanh(qb + (a0 + a1) + (a2 + a3));
        float s = v * vr;
#pragma unroll
        for (int off = 32; off > 0; off >>= 1) s += __shfl_xor(s, off);
        if (lane == 0) score[(size_t)d * TT + t] = s + vb;
    }
}

// ---------------------------------------------------------------------------
// Kernel 4: per-day softmax over T + ctx[d][j] = sum_t attn * y
// ---------------------------------------------------------------------------
__global__ __launch_bounds__(256) void ctx_kernel(
    const float* __restrict__ score, const float* __restrict__ y,
    float* __restrict__ ctx)
{
    const int d = blockIdx.x;
    const int tid = threadIdx.x;
    __shared__ float red[256];
    const float* sc = score + (size_t)d * TT;

    float m = -1e30f;
    for (int t = tid; t < TT; t += 256) m = fmaxf(m, sc[t]);
    red[tid] = m; __syncthreads();
    for (int s = 128; s > 0; s >>= 1) {
        if (tid < s) red[tid] = fmaxf(red[tid], red[tid + s]);
        __syncthreads();
    }
    m = red[0]; __syncthreads();

    float se = 0.f;
    for (int t = tid; t < TT; t += 256) se += __expf(sc[t] - m);
    red[tid] = se; __syncthreads();
    for (int s = 128; s > 0; s >>= 1) {
        if (tid < s) red[tid] += red[tid + s];
        __syncthreads();
    }
    const float inv = 1.f / red[0];
    __syncthreads();

    const int j = tid & 63, grp = tid >> 6;
    const float* yd = y + (size_t)d * TT * HH;
    float a = 0.f;
    for (int t = grp; t < TT; t += 4)
        a = fmaf(__expf(sc[t] - m), yd[(size_t)t * HH + j], a);
    red[tid] = a; __syncthreads();
    if (tid < 64)
        ctx[d * 64 + tid] =
            (red[tid] + red[tid + 64] + red[tid + 128] + red[tid + 192]) * inv;
}

// ---------------------------------------------------------------------------
// Kernel 5: day LSTM (1 step) + day attention + stock head -> out[1]
// ---------------------------------------------------------------------------
__global__ __launch_bounds__(320) void final_kernel(
    const float* __restrict__ ctx,
    const float* __restrict__ Wih, const float* __restrict__ bih,
    const float* __restrict__ bhh,
    const float* __restrict__ W1, const float* __restrict__ b1,
    const float* __restrict__ W2, const float* __restrict__ b2,
    const float* __restrict__ Vw, const float* __restrict__ Vb,
    const float* __restrict__ stw, const float* __restrict__ stb,
    float* __restrict__ out)
{
    const int tid = threadIdx.x;
    const int dd = tid >> 6, j = tid & 63;
    __shared__ __align__(16) float ctxs[320];
    __shared__ float gsh[5 * 256];
    __shared__ __align__(16) float fulls[320];
    __shared__ __align__(16) float lasts[320];
    __shared__ float s2[5];

    ctxs[tid] = ctx[tid];
    __syncthreads();

    if (tid < 256) {
        float w[64];
#pragma unroll
        for (int k = 0; k < 16; k++) {
            float4 v = *(const float4*)&Wih[tid * 64 + 4 * k];
            w[4 * k] = v.x; w[4 * k + 1] = v.y;
            w[4 * k + 2] = v.z; w[4 * k + 3] = v.w;
        }
        const float bb = bih[tid] + bhh[tid];
        for (int dday = 0; dday < 5; ++dday) {
            float acc = bb;
#pragma unroll
            for (int k = 0; k < 64; k += 4) {
                float4 c4 = *(const float4*)&ctxs[dday * 64 + k];
                acc += w[k] * c4.x + w[k + 1] * c4.y + w[k + 2] * c4.z +
                       w[k + 3] * c4.w;
            }
            gsh[dday * 256 + tid] = acc;
        }
    }
    __syncthreads();
    {
        float gi = gsh[dd * 256 + j];
        float gg2 = gsh[dd * 256 + 128 + j];
        float go = gsh[dd * 256 + 192 + j];
        float c = fast_sig(gi) * fast_tanh(gg2);
        float hd = fast_sig(go) * fast_tanh(c);
        lasts[tid] = hd;
        fulls[tid] = fast_tanh(hd);
    }
    __syncthreads();
    {
        float w1r[64], w2r[64];
#pragma unroll
        for (int k = 0; k < 16; k++) {
            float4 v1 = *(const float4*)&W1[j * 64 + 4 * k];
            float4 v2 = *(const float4*)&W2[j * 64 + 4 * k];
            w1r[4 * k] = v1.x; w1r[4 * k + 1] = v1.y;
            w1r[4 * k + 2] = v1.z; w1r[4 * k + 3] = v1.w;
            w2r[4 * k] = v2.x; w2r[4 * k + 1] = v2.y;
            w2r[4 * k + 2] = v2.z; w2r[4 * k + 3] = v2.w;
        }
        float acc = b1[j] + b2[j];
#pragma unroll
        for (int k = 0; k < 64; ++k)
            acc += w1r[k] * lasts[dd * 64 + k] + w2r[k] * fulls[dd * 64 + k];
        float v = fast_tanh(acc) * Vw[j];
#pragma unroll
        for (int off = 32; off > 0; off >>= 1) v += __shfl_xor(v, off);
        if (j == 0) s2[dd] = v + Vb[0];
    }
    __syncthreads();
    if (tid < 64) {
        float m = s2[0];
#pragma unroll
        for (int dday = 1; dday < 5; ++dday) m = fmaxf(m, s2[dday]);
        float se = 0.f, ft = 0.f;
#pragma unroll
        for (int dday = 0; dday < 5; ++dday) {
            float e = __expf(s2[dday] - m);
            se += e;
            ft += e * fulls[dday * 64 + tid];
        }
        ft /= se;
        float pv = ft * stw[tid];
#pragma unroll
        for (int off = 32; off > 0; off >>= 1) pv += __shfl_xor(pv, off);
        if (tid == 0) out[0] = 3.f * fast_tanh(pv + stb[0]);
    }
}

// ---------------------------------------------------------------------------
extern "C" void kernel_launch(void* const* d_in, const int* in_sizes, int n_in,
                              void* d_out, int out_size, void* d_ws,
                              size_t ws_size, hipStream_t stream)
{
    const float* x     = (const float*)d_in[0];
    const float* ts    = (const float*)d_in[1];
    const float* Wallw = (const float*)d_in[3];
    const float* Wallb = (const float*)d_in[4];
    const float* Uallw = (const float*)d_in[5];
    const float* Uallb = (const float*)d_in[6];
    const float* Wdw   = (const float*)d_in[7];
    const float* Wdb   = (const float*)d_in[8];
    const float* taW1w = (const float*)d_in[9];
    const float* taW1b = (const float*)d_in[10];
    const float* taW2w = (const float*)d_in[11];
    const float* taW2b = (const float*)d_in[12];
    const float* taVw  = (const float*)d_in[13];
    const float* taVb  = (const float*)d_in[14];
    const float* Wih   = (const float*)d_in[15];
    const float* bih   = (const float*)d_in[17];
    const float* bhh   = (const float*)d_in[18];
    const float* daW1w = (const float*)d_in[19];
    const float* daW1b = (const float*)d_in[20];
    const float* daW2w = (const float*)d_in[21];
    const float* daW2b = (const float*)d_in[22];
    const float* daVw  = (const float*)d_in[23];
    const float* daVb  = (const float*)d_in[24];
    const float* stw   = (const float*)d_in[25];
    const float* stb   = (const float*)d_in[26];
    float* out = (float*)d_out;

    float* ux = (float*)d_ws;                       // [5][8192][256]
    float* yb = ux + (size_t)DDAYS * TT * GG;       // [5][8192][64]
    float* sc = yb + (size_t)DDAYS * TT * HH;       // [5][8192]
    float* hf = sc + (size_t)DDAYS * TT;            // [5][64]
    float* cx = hf + 512;                           // [5][64]

    gemm_ux<<<dim3(320, 2), 256, 0, stream>>>(x, Uallw, ux);
    scan_kernel<<<dim3(DDAYS), 64, 0, stream>>>(ux, ts, Wallw, Wallb, Uallb,
                                                Wdw, Wdb, yb, hf);
    score_kernel<<<dim3(TT / (4 * TW), DDAYS), 256, 0, stream>>>(
        yb, hf, taW1w, taW1b, taW2w, taW2b, taVw, taVb, sc);
    ctx_kernel<<<dim3(DDAYS), 256, 0, stream>>>(sc, yb, cx);
    final_kernel<<<dim3(1), 320, 0, stream>>>(cx, Wih, bih, bhh, daW1w, daW1b,
                                              daW2w, daW2b, daVw, daVb, stw,
                                              stb, out);
}

// Round 11
// 5682.007 us; speedup vs baseline: 1.1824x; 1.1824x over previous
//
#include <hip/hip_runtime.h>
#include <hip/hip_bf16.h>
#include <hip/hip_fp16.h>
#include <cstdint>

#define DDAYS 5
#define TT 8192
#define FF 768
#define HH 64
#define GG 256  // 4*H

__device__ __forceinline__ float fast_tanh(float x) {
    return 1.f - 2.f / (__expf(2.f * x) + 1.f);
}
__device__ __forceinline__ float fast_sig(float x) {
    return 1.f / (1.f + __expf(-x));
}

// ---------------------------------------------------------------------------
// Kernel 1: ux[m][g] = sum_f A[m][f] * B[g][f]   (bias added later in scan)
// ---------------------------------------------------------------------------
__global__ __launch_bounds__(256, 2) void gemm_ux(
    const float* __restrict__ A, const float* __restrict__ B,
    float* __restrict__ C)
{
    __shared__ __align__(16) float As[16][132];
    __shared__ __align__(16) float Bs[16][132];
    const int tid = threadIdx.x;
    const int m0 = blockIdx.x * 128;
    const int n0 = blockIdx.y * 128;
    const int tx = tid & 15, ty = tid >> 4;
    const int i0 = tx * 8, j0 = ty * 8;
    const int lrow = tid >> 2, lc4 = tid & 3;

    const float* Ap = A + (size_t)(m0 + lrow) * FF + lc4 * 4;
    const float* Bp = B + (size_t)(n0 + lrow) * FF + lc4 * 4;

    float4 pa0 = *(const float4*)(Ap);
    float4 pa1 = *(const float4*)(Ap + 64 * FF);
    float4 pb0 = *(const float4*)(Bp);
    float4 pb1 = *(const float4*)(Bp + 64 * FF);

    float acc[8][8] = {};

    for (int kt = 0; kt < FF / 16; ++kt) {
        __syncthreads();
        {
            const int kk = lc4 * 4;
            As[kk + 0][lrow] = pa0.x; As[kk + 1][lrow] = pa0.y;
            As[kk + 2][lrow] = pa0.z; As[kk + 3][lrow] = pa0.w;
            As[kk + 0][lrow + 64] = pa1.x; As[kk + 1][lrow + 64] = pa1.y;
            As[kk + 2][lrow + 64] = pa1.z; As[kk + 3][lrow + 64] = pa1.w;
            Bs[kk + 0][lrow] = pb0.x; Bs[kk + 1][lrow] = pb0.y;
            Bs[kk + 2][lrow] = pb0.z; Bs[kk + 3][lrow] = pb0.w;
            Bs[kk + 0][lrow + 64] = pb1.x; Bs[kk + 1][lrow + 64] = pb1.y;
            Bs[kk + 2][lrow + 64] = pb1.z; Bs[kk + 3][lrow + 64] = pb1.w;
        }
        __syncthreads();
        if (kt + 1 < FF / 16) {
            const int k0 = (kt + 1) * 16;
            pa0 = *(const float4*)(Ap + k0);
            pa1 = *(const float4*)(Ap + 64 * FF + k0);
            pb0 = *(const float4*)(Bp + k0);
            pb1 = *(const float4*)(Bp + 64 * FF + k0);
        }
#pragma unroll
        for (int k = 0; k < 16; ++k) {
            float a[8], b[8];
            *(float4*)&a[0] = *(const float4*)&As[k][i0];
            *(float4*)&a[4] = *(const float4*)&As[k][i0 + 4];
            *(float4*)&b[0] = *(const float4*)&Bs[k][j0];
            *(float4*)&b[4] = *(const float4*)&Bs[k][j0 + 4];
#pragma unroll
            for (int r = 0; r < 8; ++r)
#pragma unroll
                for (int c = 0; c < 8; ++c)
                    acc[r][c] = fmaf(a[r], b[c], acc[r][c]);
        }
    }
#pragma unroll
    for (int r = 0; r < 8; ++r) {
        float4 s0 = make_float4(acc[r][0], acc[r][1], acc[r][2], acc[r][3]);
        float4 s1 = make_float4(acc[r][4], acc[r][5], acc[r][6], acc[r][7]);
        float* Cp = C + (size_t)(m0 + i0 + r) * GG + n0 + j0;
        *(float4*)Cp = s0;
        *(float4*)(Cp + 4) = s1;
    }
}

// ---------------------------------------------------------------------------
// Kernel 2: TimeLSTM scan. One block (2 waves = 128 thr) per day.
// R11 = R5 structure (2 waves; lane=(g0,jl); wave owns 32 cols; lane computes
// 2 gate rows; gates/p exchanged by 3x shfl_xor(32); h,c f16 double-buffered
// in LDS; raw lgkm-only barrier) with the dot math switched from the R5
// cvt+fma fallback (~408 instrs/step/wave, issue-dominated at 58% busy) to
// real __hfma2 (v_pk_fma_f16) chains (~130 instrs). The 80-reg/lane weight
// set is the size the allocator PROVABLY keeps resident (R5: VGPR=104;
// 160-reg variants remat every step -- R8/R9/R10).
// Accuracy: f16 accumulator chains passed with absmax 0.0 in R10.
// ---------------------------------------------------------------------------
__global__ __launch_bounds__(128, 1) void scan_kernel(
    const float* __restrict__ ux, const float* __restrict__ ts,
    const float* __restrict__ Ww, const float* __restrict__ Wb,
    const float* __restrict__ Ub,
    const float* __restrict__ Dw, const float* __restrict__ Db,
    float* __restrict__ y, float* __restrict__ hfin)
{
    const int d = blockIdx.x;
    const int tid = threadIdx.x;
    const int wv = tid >> 6;
    const int l  = tid & 63;
    const int jl = l & 31;
    const int g0 = l >> 5;
    const int jj = (wv << 5) | jl;        // column 0..63
    const int rA = (g0 << 6) + jj;        // f (g0=0) / i (g0=1)
    const int rB = 128 + (g0 << 6) + jj;  // o (g0=0) / g (g0=1)

    // one-time: convert this lane's weight rows to __half2 (80 regs total)
    __half2 wA[32], wB[32], wdr[16];
    {
        const float2* pA = (const float2*)(Ww + (size_t)rA * 64);
        const float2* pB = (const float2*)(Ww + (size_t)rB * 64);
#pragma unroll
        for (int k = 0; k < 32; ++k) {
            float2 a = pA[k], b = pB[k];
            wA[k] = __floats2half2_rn(a.x, a.y);
            wB[k] = __floats2half2_rn(b.x, b.y);
        }
        const float2* pD = (const float2*)(Dw + (size_t)jj * 64 + (g0 << 5));
#pragma unroll
        for (int k = 0; k < 16; ++k) {
            float2 v = pD[k];
            wdr[k] = __floats2half2_rn(v.x, v.y);
        }
    }
    const float biasA = Wb[rA] + Ub[rA];
    const float biasB = Wb[rB] + Ub[rB];
    const float wdb = Db[jj];
    // gB activation: sigmoid for o (g0=0), tanh for g (g0=1): tanh(x)=2*sig(2x)-1
    const float bmul = g0 ? 2.f : 1.f;
    const float bsub = g0 ? 1.f : 0.f;

    __shared__ __align__(16) __half h_lds[2][64];
    __shared__ __align__(16) __half c_lds[2][64];
    if (tid < 64) {
        h_lds[0][tid] = __float2half(0.f);
        c_lds[0][tid] = __float2half(0.f);
    }
    __syncthreads();

    const float* uxd  = ux + (size_t)d * TT * GG;
    const float* uA_p = uxd + rA;
    const float* uB_p = uxd + rB;
    const float* tsd  = ts + (size_t)d * TT;
    float* yd = y + (size_t)d * TT * HH;

    float uA[4], uB[4], tp[4];
#pragma unroll
    for (int i = 0; i < 4; ++i) {
        uA[i] = uA_p[(size_t)i * GG];
        uB[i] = uB_p[(size_t)i * GG];
        tp[i] = tsd[i];
    }

    float c_old = 0.f;

    for (int t = 0; t < TT; t += 4) {
#pragma unroll
        for (int i = 0; i < 4; ++i) {
            const int tc = t + i;
            const int rb = tc & 1, nb = rb ^ 1;
            const float ucA = uA[i], ucB = uB[i], tcur = tp[i];
            {   // prefetch step tc+4 (stays in flight across the raw barrier)
                int tn = tc + 4; if (tn > TT - 1) tn = TT - 1;
                uA[i] = uA_p[(size_t)tn * GG];
                uB[i] = uB_p[(size_t)tn * GG];
                tp[i] = tsd[tn];
            }

            // h: 64 f16 = 8x ds_read_b128 (broadcast)
            __half2 hp[32];
            {
                const uint4* hb = (const uint4*)&h_lds[rb][0];
#pragma unroll
                for (int k = 0; k < 8; ++k) {
                    uint4 v = hb[k];
                    hp[4 * k + 0] = __builtin_bit_cast(__half2, v.x);
                    hp[4 * k + 1] = __builtin_bit_cast(__half2, v.y);
                    hp[4 * k + 2] = __builtin_bit_cast(__half2, v.z);
                    hp[4 * k + 3] = __builtin_bit_cast(__half2, v.w);
                }
            }
            // c half (this lane's k-range): 32 f16 = 4x ds_read_b128
            __half2 cp[16];
            {
                const uint4* cb = (const uint4*)(&c_lds[rb][0] + (g0 << 5));
#pragma unroll
                for (int k = 0; k < 4; ++k) {
                    uint4 v = cb[k];
                    cp[4 * k + 0] = __builtin_bit_cast(__half2, v.x);
                    cp[4 * k + 1] = __builtin_bit_cast(__half2, v.y);
                    cp[4 * k + 2] = __builtin_bit_cast(__half2, v.z);
                    cp[4 * k + 3] = __builtin_bit_cast(__half2, v.w);
                }
            }

            // two row-dots over h + half-dot over c, f16 pair chains
            const __half2 z2 = __float2half2_rn(0.f);
            __half2 aA0 = z2, aA1 = z2, aB0 = z2, aB1 = z2;
            __half2 aD0 = z2, aD1 = z2;
#pragma unroll
            for (int k = 0; k < 32; k += 2) {
                aA0 = __hfma2(wA[k],     hp[k],     aA0);
                aA1 = __hfma2(wA[k + 1], hp[k + 1], aA1);
                aB0 = __hfma2(wB[k],     hp[k],     aB0);
                aB1 = __hfma2(wB[k + 1], hp[k + 1], aB1);
            }
#pragma unroll
            for (int k = 0; k < 16; k += 2) {
                aD0 = __hfma2(wdr[k],     cp[k],     aD0);
                aD1 = __hfma2(wdr[k + 1], cp[k + 1], aD1);
            }
            const float dA = (__low2float(aA0) + __low2float(aA1)) +
                             (__high2float(aA0) + __high2float(aA1));
            const float dB = (__low2float(aB0) + __low2float(aB1)) +
                             (__high2float(aB0) + __high2float(aB1));
            float p = (__low2float(aD0) + __low2float(aD1)) +
                      (__high2float(aD0) + __high2float(aD1));
            p += __shfl_xor(p, 32);
            const float cs1 = fast_tanh(p + wdb);

            const float preA = dA + biasA + ucA;
            const float preB = dB + biasB + ucB;
            const float gA = fast_sig(preA);                 // f or i
            const float q  = fast_sig(preB * bmul);
            const float gB = fmaf(q, bmul, -bsub);           // o (sig) or g (tanh)

            const float gA2 = __shfl_xor(gA, 32);
            const float gB2 = __shfl_xor(gB, 32);
            const float f  = g0 ? gA2 : gA;
            const float ii = g0 ? gA  : gA2;
            const float oo = g0 ? gB2 : gB;
            const float gg = g0 ? gB  : gB2;

            const float cadj = fmaf(cs1, tcur - 1.f, c_old);
            const float cn = fmaf(f, cadj, ii * gg);
            const float hn = oo * fast_tanh(cn);
            c_old = cn;

            if (g0 == 0) {
                h_lds[nb][jj] = __float2half(hn);
                yd[(size_t)tc * HH + jj] = fast_tanh(gB);    // y = tanh(sig(o_pre))
            } else {
                c_lds[nb][jj] = __float2half(cn);
            }

            // raw barrier: LDS-visibility only; global prefetches stay in flight
            asm volatile("s_waitcnt lgkmcnt(0)" ::: "memory");
            __builtin_amdgcn_sched_barrier(0);
            __builtin_amdgcn_s_barrier();
            __builtin_amdgcn_sched_barrier(0);
        }
    }
    // final state: step TT-1 wrote buffer 0 (TT even)
    if (tid < 64) hfin[d * 64 + tid] = __half2float(h_lds[0][tid]);
}

// ---------------------------------------------------------------------------
// Kernel 3: score[d][t] = V . tanh(q_d + W2 y_dt + b2) + Vb
// ---------------------------------------------------------------------------
#define TW 32
__global__ __launch_bounds__(256) void score_kernel(
    const float* __restrict__ y, const float* __restrict__ hfin,
    const float* __restrict__ W1, const float* __restrict__ b1,
    const float* __restrict__ W2, const float* __restrict__ b2,
    const float* __restrict__ Vw, const float* __restrict__ Vb,
    float* __restrict__ score)
{
    const int d = blockIdx.y;
    const int tid = threadIdx.x;
    const int lane = tid & 63, wv = tid >> 6;
    __shared__ __align__(16) float hf[64];
    __shared__ float qs[64];
    if (tid < 64) hf[tid] = hfin[d * 64 + tid];
    __syncthreads();
    if (tid < 64) {
        float acc = b1[tid];
#pragma unroll
        for (int k = 0; k < 16; k++) {
            float4 w = *(const float4*)&W1[tid * 64 + 4 * k];
            float4 h4 = *(const float4*)&hf[4 * k];
            acc += w.x * h4.x + w.y * h4.y + w.z * h4.z + w.w * h4.w;
        }
        qs[tid] = acc;
    }
    __syncthreads();

    float w2[64];
#pragma unroll
    for (int k = 0; k < 16; k++) {
        float4 v = *(const float4*)&W2[lane * 64 + 4 * k];
        w2[4 * k] = v.x; w2[4 * k + 1] = v.y;
        w2[4 * k + 2] = v.z; w2[4 * k + 3] = v.w;
    }
    const float qb = qs[lane] + b2[lane];
    const float vr = Vw[lane];
    const float vb = Vb[0];
    const int tbase = blockIdx.x * (4 * TW) + wv * TW;
    const float* yd = y + (size_t)d * TT * HH;

    for (int i = 0; i < TW; i++) {
        const int t = tbase + i;
        const float* yrow = yd + (size_t)t * HH;
        float a0 = 0.f, a1 = 0.f, a2 = 0.f, a3 = 0.f;
#pragma unroll
        for (int k = 0; k < 64; k += 4) {
            float4 yv = *(const float4*)&yrow[k];
            a0 = fmaf(yv.x, w2[k], a0);
            a1 = fmaf(yv.y, w2[k + 1], a1);
            a2 = fmaf(yv.z, w2[k + 2], a2);
            a3 = fmaf(yv.w, w2[k + 3], a3);
        }
        float v = fast_tanh(qb + (a0 + a1) + (a2 + a3));
        float s = v * vr;
#pragma unroll
        for (int off = 32; off > 0; off >>= 1) s += __shfl_xor(s, off);
        if (lane == 0) score[(size_t)d * TT + t] = s + vb;
    }
}

// ---------------------------------------------------------------------------
// Kernel 4: per-day softmax over T + ctx[d][j] = sum_t attn * y
// ---------------------------------------------------------------------------
__global__ __launch_bounds__(256) void ctx_kernel(
    const float* __restrict__ score, const float* __restrict__ y,
    float* __restrict__ ctx)
{
    const int d = blockIdx.x;
    const int tid = threadIdx.x;
    __shared__ float red[256];
    const float* sc = score + (size_t)d * TT;

    float m = -1e30f;
    for (int t = tid; t < TT; t += 256) m = fmaxf(m, sc[t]);
    red[tid] = m; __syncthreads();
    for (int s = 128; s > 0; s >>= 1) {
        if (tid < s) red[tid] = fmaxf(red[tid], red[tid + s]);
        __syncthreads();
    }
    m = red[0]; __syncthreads();

    float se = 0.f;
    for (int t = tid; t < TT; t += 256) se += __expf(sc[t] - m);
    red[tid] = se; __syncthreads();
    for (int s = 128; s > 0; s >>= 1) {
        if (tid < s) red[tid] += red[tid + s];
        __syncthreads();
    }
    const float inv = 1.f / red[0];
    __syncthreads();

    const int j = tid & 63, grp = tid >> 6;
    const float* yd = y + (size_t)d * TT * HH;
    float a = 0.f;
    for (int t = grp; t < TT; t += 4)
        a = fmaf(__expf(sc[t] - m), yd[(size_t)t * HH + j], a);
    red[tid] = a; __syncthreads();
    if (tid < 64)
        ctx[d * 64 + tid] =
            (red[tid] + red[tid + 64] + red[tid + 128] + red[tid + 192]) * inv;
}

// ---------------------------------------------------------------------------
// Kernel 5: day LSTM (1 step) + day attention + stock head -> out[1]
// ---------------------------------------------------------------------------
__global__ __launch_bounds__(320) void final_kernel(
    const float* __restrict__ ctx,
    const float* __restrict__ Wih, const float* __restrict__ bih,
    const float* __restrict__ bhh,
    const float* __restrict__ W1, const float* __restrict__ b1,
    const float* __restrict__ W2, const float* __restrict__ b2,
    const float* __restrict__ Vw, const float* __restrict__ Vb,
    const float* __restrict__ stw, const float* __restrict__ stb,
    float* __restrict__ out)
{
    const int tid = threadIdx.x;
    const int dd = tid >> 6, j = tid & 63;
    __shared__ __align__(16) float ctxs[320];
    __shared__ float gsh[5 * 256];
    __shared__ __align__(16) float fulls[320];
    __shared__ __align__(16) float lasts[320];
    __shared__ float s2[5];

    ctxs[tid] = ctx[tid];
    __syncthreads();

    if (tid < 256) {
        float w[64];
#pragma unroll
        for (int k = 0; k < 16; k++) {
            float4 v = *(const float4*)&Wih[tid * 64 + 4 * k];
            w[4 * k] = v.x; w[4 * k + 1] = v.y;
            w[4 * k + 2] = v.z; w[4 * k + 3] = v.w;
        }
        const float bb = bih[tid] + bhh[tid];
        for (int dday = 0; dday < 5; ++dday) {
            float acc = bb;
#pragma unroll
            for (int k = 0; k < 64; k += 4) {
                float4 c4 = *(const float4*)&ctxs[dday * 64 + k];
                acc += w[k] * c4.x + w[k + 1] * c4.y + w[k + 2] * c4.z +
                       w[k + 3] * c4.w;
            }
            gsh[dday * 256 + tid] = acc;
        }
    }
    __syncthreads();
    {
        float gi = gsh[dd * 256 + j];
        float gg2 = gsh[dd * 256 + 128 + j];
        float go = gsh[dd * 256 + 192 + j];
        float c = fast_sig(gi) * fast_tanh(gg2);
        float hd = fast_sig(go) * fast_tanh(c);
        lasts[tid] = hd;
        fulls[tid] = fast_tanh(hd);
    }
    __syncthreads();
    {
        float w1r[64], w2r[64];
#pragma unroll
        for (int k = 0; k < 16; k++) {
            float4 v1 = *(const float4*)&W1[j * 64 + 4 * k];
            float4 v2 = *(const float4*)&W2[j * 64 + 4 * k];
            w1r[4 * k] = v1.x; w1r[4 * k + 1] = v1.y;
            w1r[4 * k + 2] = v1.z; w1r[4 * k + 3] = v1.w;
            w2r[4 * k] = v2.x; w2r[4 * k + 1] = v2.y;
            w2r[4 * k + 2] = v2.z; w2r[4 * k + 3] = v2.w;
        }
        float acc = b1[j] + b2[j];
#pragma unroll
        for (int k = 0; k < 64; ++k)
            acc += w1r[k] * lasts[dd * 64 + k] + w2r[k] * fulls[dd * 64 + k];
        float v = fast_tanh(acc) * Vw[j];
#pragma unroll
        for (int off = 32; off > 0; off >>= 1) v += __shfl_xor(v, off);
        if (j == 0) s2[dd] = v + Vb[0];
    }
    __syncthreads();
    if (tid < 64) {
        float m = s2[0];
#pragma unroll
        for (int dday = 1; dday < 5; ++dday) m = fmaxf(m, s2[dday]);
        float se = 0.f, ft = 0.f;
#pragma unroll
        for (int dday = 0; dday < 5; ++dday) {
            float e = __expf(s2[dday] - m);
            se += e;
            ft += e * fulls[dday * 64 + tid];
        }
        ft /= se;
        float pv = ft * stw[tid];
#pragma unroll
        for (int off = 32; off > 0; off >>= 1) pv += __shfl_xor(pv, off);
        if (tid == 0) out[0] = 3.f * fast_tanh(pv + stb[0]);
    }
}

// ---------------------------------------------------------------------------
extern "C" void kernel_launch(void* const* d_in, const int* in_sizes, int n_in,
                              void* d_out, int out_size, void* d_ws,
                              size_t ws_size, hipStream_t stream)
{
    const float* x     = (const float*)d_in[0];
    const float* ts    = (const float*)d_in[1];
    const float* Wallw = (const float*)d_in[3];
    const float* Wallb = (const float*)d_in[4];
    const float* Uallw = (const float*)d_in[5];
    const float* Uallb = (const float*)d_in[6];
    const float* Wdw   = (const float*)d_in[7];
    const float* Wdb   = (const float*)d_in[8];
    const float* taW1w = (const float*)d_in[9];
    const float* taW1b = (const float*)d_in[10];
    const float* taW2w = (const float*)d_in[11];
    const float* taW2b = (const float*)d_in[12];
    const float* taVw  = (const float*)d_in[13];
    const float* taVb  = (const float*)d_in[14];
    const float* Wih   = (const float*)d_in[15];
    const float* bih   = (const float*)d_in[17];
    const float* bhh   = (const float*)d_in[18];
    const float* daW1w = (const float*)d_in[19];
    const float* daW1b = (const float*)d_in[20];
    const float* daW2w = (const float*)d_in[21];
    const float* daW2b = (const float*)d_in[22];
    const float* daVw  = (const float*)d_in[23];
    const float* daVb  = (const float*)d_in[24];
    const float* stw   = (const float*)d_in[25];
    const float* stb   = (const float*)d_in[26];
    float* out = (float*)d_out;

    float* ux = (float*)d_ws;                       // [5][8192][256]
    float* yb = ux + (size_t)DDAYS * TT * GG;       // [5][8192][64]
    float* sc = yb + (size_t)DDAYS * TT * HH;       // [5][8192]
    float* hf = sc + (size_t)DDAYS * TT;            // [5][64]
    float* cx = hf + 512;                           // [5][64]

    gemm_ux<<<dim3(320, 2), 256, 0, stream>>>(x, Uallw, ux);
    scan_kernel<<<dim3(DDAYS), 128, 0, stream>>>(ux, ts, Wallw, Wallb, Uallb,
                                                 Wdw, Wdb, yb, hf);
    score_kernel<<<dim3(TT / (4 * TW), DDAYS), 256, 0, stream>>>(
        yb, hf, taW1w, taW1b, taW2w, taW2b, taVw, taVb, sc);
    ctx_kernel<<<dim3(DDAYS), 256, 0, stream>>>(sc, yb, cx);
    final_kernel<<<dim3(1), 320, 0, stream>>>(cx, Wih, bih, bhh, daW1w, daW1b,
                                              daW2w, daW2b, daVw, daVb, stw,
                                              stb, out);
}